// Round 5
// baseline (40.623 us; speedup 1.0000x reference)
//
#include <hip/hip_runtime.h>
#include <math.h>
#include <stdint.h>

namespace {

constexpr int kB = 16384;
constexpr int kN = 12;
constexpr int kD = 64;
constexpr int kL = 2;
constexpr int kH = kN * kD;          // 768
constexpr float kEps = 1e-5f;

constexpr int WAVES_PER_BLOCK = 4;
constexpr int BLOCK = 64 * WAVES_PER_BLOCK;        // 256
constexpr int GRID  = kB / (2 * WAVES_PER_BLOCK);  // 2048 -> 2 graphs/wave, 8 blocks/CU

typedef _Float16 half2v __attribute__((ext_vector_type(2)));

__device__ __forceinline__ uint32_t pack_f16(float a, float b) {
    auto p = __builtin_amdgcn_cvt_pkrtz(a, b);   // __fp16 ext_vector(2)
    return __builtin_bit_cast(uint32_t, p);
}

// x += row_ror:N of x (within the 16-lane DPP row).
template<int N>
__device__ __forceinline__ float dpp_ror_add(float x) {
    int r = __builtin_amdgcn_update_dpp(0, __builtin_bit_cast(int, x),
                                        0x120 + N, 0xF, 0xF, true);
    return x + __builtin_bit_cast(float, r);
}
// Sum over a 32-lane group (two DPP rows); every lane gets the total.
__device__ __forceinline__ float rowSum32(float x) {
    x = dpp_ror_add<8>(x);
    x = dpp_ror_add<4>(x);
    x = dpp_ror_add<2>(x);
    x = dpp_ror_add<1>(x);
    int sw = __builtin_amdgcn_ds_swizzle(__builtin_bit_cast(int, x), 0x401F); // xor 16
    return x + __builtin_bit_cast(float, sw);
}

// tanh-form GELU (max err vs exact ~1.5e-3, overflow-graceful).
__device__ __forceinline__ float fast_gelu(float x) {
    const float x2 = x * x;
    const float y  = x * fmaf(x2, 0.0356774081f, 0.7978845608f);
    const float e  = __expf(2.0f * y);
    const float r  = __builtin_amdgcn_rcpf(e + 1.0f);
    const float t  = fmaf(-2.0f, r, 1.0f);      // tanh(y)
    const float hx = 0.5f * x;
    return fmaf(hx, t, hx);
}

__global__ __launch_bounds__(BLOCK, 8)
void gnn_fused(const float* __restrict__ x,
               const float* __restrict__ mp_w,
               const float* __restrict__ mp_b,
               const float* __restrict__ attn_w,
               const float* __restrict__ ln_g,
               const float* __restrict__ ln_b,
               const float* __restrict__ cls_w,
               const float* __restrict__ cls_b,
               float* __restrict__ out)
{
    // W f16-packed along d: WI[l][d4][e][p] = half2(W[4d4+2p][e], W[4d4+2p+1][e])
    // (W[d][e] = mp_w[l][e][d]).  16 KB.
    __shared__ __align__(16) uint32_t WIu[kL * 16 * kD * 2];
    __shared__ __align__(16) float w2s[kL][kD];
    __shared__ __align__(16) float mpb[kL][kD];
    __shared__ __align__(16) float lng[kL][kD];
    __shared__ __align__(16) float lnb[kL][kD];
    __shared__ __align__(16) uint32_t qpu[WAVES_PER_BLOCK][2][36]; // q half2, padded pitch

    const int tid  = threadIdx.x;
    const int lane = tid & 63;
    const int wid  = tid >> 6;
    const int grp  = lane >> 5;        // graph slot in wave (0..1)
    const int sub  = lane & 31;        // lane in graph; owns feats 2sub, 2sub+1
    const int b    = (blockIdx.x * WAVES_PER_BLOCK + wid) * 2 + grp;

    // ---- issue x loads early (overlap with LDS staging) ----
    float2 h2[kN];
    const float* xb = x + b * kH + 2 * sub;
#pragma unroll
    for (int n = 0; n < kN; ++n)
        h2[n] = *(const float2*)(xb + n * kD);

    // ---- stage W (f16-packed) + params ----
    for (int i = tid; i < kL * kD * 16; i += BLOCK) {
        const int d4 = i & 15;
        const int e  = (i >> 4) & 63;
        const int l  = i >> 10;
        const float4 w = *(const float4*)&mp_w[(l * kD + e) * kD + 4 * d4]; // coalesced
        uint2 pk;
        pk.x = pack_f16(w.x, w.y);
        pk.y = pack_f16(w.z, w.w);
        *(uint2*)&WIu[((l * 16 + d4) * kD + e) * 2] = pk;
    }
    for (int i = tid; i < kL * kD; i += BLOCK) {
        const int l = i >> 6, d = i & 63;
        w2s[l][d] = attn_w[l * (2 * kD) + kD + d];  // w2 half; w1 + attn_b cancel in softmax
        mpb[l][d] = mp_b[i];
        lng[l][d] = ln_g[i];
        lnb[l][d] = ln_b[i];
    }
    __syncthreads();

#pragma unroll
    for (int l = 0; l < kL; ++l) {
        const float2 w2v = *(const float2*)&w2s[l][2 * sub];

        // ---- ej -> exp -> sum & q, fused. |ej| <~ 1 (w2 scale 0.02), no max needed.
        float sum = 0.f;
        float2 q = make_float2(0.f, 0.f);
#pragma unroll
        for (int n = 0; n < kN; ++n) {
            float v = fmaf(h2[n].y, w2v.y, h2[n].x * w2v.x);
            v = rowSum32(v);                 // ej[n], uniform in group
            const float sn = __expf(v);
            sum += sn;
            q.x = fmaf(sn, h2[n].x, q.x);
            q.y = fmaf(sn, h2[n].y, q.y);
        }
        const float inv = __builtin_amdgcn_rcpf(sum);

        // publish q (f16 pair) for the group
        qpu[wid][grp][sub] = pack_f16(q.x, q.y);
        __builtin_amdgcn_wave_barrier();

        // ---- agg[e] = inv * sum_d q[d] W[d][e] + mp_b[e]; lane owns e=2sub,2sub+1
        float cx = 0.f, cy = 0.f;
        const uint32_t* wbase = &WIu[(l * 16) * (kD * 2) + 4 * sub];
        const uint32_t* qrow  = &qpu[wid][grp][0];
#pragma unroll
        for (int d8 = 0; d8 < 8; ++d8) {     // two d4-steps per iter
            const uint4 qv = *(const uint4*)&qrow[4 * d8];
            const uint4 w0 = *(const uint4*)&wbase[(2 * d8 + 0) * (kD * 2)];
            const uint4 w1 = *(const uint4*)&wbase[(2 * d8 + 1) * (kD * 2)];
            const half2v qa = __builtin_bit_cast(half2v, qv.x);
            const half2v qb = __builtin_bit_cast(half2v, qv.y);
            const half2v qc = __builtin_bit_cast(half2v, qv.z);
            const half2v qd = __builtin_bit_cast(half2v, qv.w);
            cx = __builtin_amdgcn_fdot2(qa, __builtin_bit_cast(half2v, w0.x), cx, false);
            cx = __builtin_amdgcn_fdot2(qb, __builtin_bit_cast(half2v, w0.y), cx, false);
            cy = __builtin_amdgcn_fdot2(qa, __builtin_bit_cast(half2v, w0.z), cy, false);
            cy = __builtin_amdgcn_fdot2(qb, __builtin_bit_cast(half2v, w0.w), cy, false);
            cx = __builtin_amdgcn_fdot2(qc, __builtin_bit_cast(half2v, w1.x), cx, false);
            cx = __builtin_amdgcn_fdot2(qd, __builtin_bit_cast(half2v, w1.y), cx, false);
            cy = __builtin_amdgcn_fdot2(qc, __builtin_bit_cast(half2v, w1.z), cy, false);
            cy = __builtin_amdgcn_fdot2(qd, __builtin_bit_cast(half2v, w1.w), cy, false);
        }
        const float2 mb2 = *(const float2*)&mpb[l][2 * sub];
        const float ccx = fmaf(cx, inv, mb2.x);
        const float ccy = fmaf(cy, inv, mb2.y);

        // ---- residual + GELU + LayerNorm ----
        const float2 g2 = *(const float2*)&lng[l][2 * sub];
        const float2 b2 = *(const float2*)&lnb[l][2 * sub];
#pragma unroll
        for (int n = 0; n < kN; ++n) {
            const float ge0 = fast_gelu(h2[n].x + ccx);
            const float ge1 = fast_gelu(h2[n].y + ccy);
            float s1 = ge0 + ge1;
            float s2 = fmaf(ge1, ge1, ge0 * ge0);
            s1 = rowSum32(s1);
            s2 = rowSum32(s2);
            const float mu  = s1 * (1.f / 64.f);
            const float var = fmaf(s2, 1.f / 64.f, -mu * mu);
            const float rs  = __builtin_amdgcn_rsqf(var + kEps);
            const float rgx = rs * g2.x;
            const float rgy = rs * g2.y;
            h2[n].x = fmaf(ge0 - mu, rgx, b2.x);
            h2[n].y = fmaf(ge1 - mu, rgy, b2.y);
        }
    }

    // ---- classifier: out[b][c] = <h, cls_w[c]> + cls_b[c] ----
    float p[4] = {0.f, 0.f, 0.f, 0.f};
#pragma unroll
    for (int n = 0; n < kN; ++n) {
        const int base = n * kD + 2 * sub;
#pragma unroll
        for (int c = 0; c < 4; ++c) {
            const float2 cw = *(const float2*)(cls_w + c * kH + base);
            p[c] = fmaf(h2[n].x, cw.x, p[c]);
            p[c] = fmaf(h2[n].y, cw.y, p[c]);
        }
    }
#pragma unroll
    for (int c = 0; c < 4; ++c) p[c] = rowSum32(p[c]);

    if (sub == 0) {
        const float4 cb = *(const float4*)cls_b;
        *(float4*)&out[b * 4] = make_float4(p[0] + cb.x, p[1] + cb.y,
                                            p[2] + cb.z, p[3] + cb.w);
    }
}

} // namespace

extern "C" void kernel_launch(void* const* d_in, const int* in_sizes, int n_in,
                              void* d_out, int out_size, void* d_ws, size_t ws_size,
                              hipStream_t stream)
{
    const float* x      = (const float*)d_in[0];
    const float* mp_w   = (const float*)d_in[1];
    const float* mp_b   = (const float*)d_in[2];
    const float* attn_w = (const float*)d_in[3];
    // d_in[4] = attn_b : cancels in softmax, unused
    const float* ln_g   = (const float*)d_in[5];
    const float* ln_b   = (const float*)d_in[6];
    const float* cls_w  = (const float*)d_in[7];
    const float* cls_b  = (const float*)d_in[8];
    float* out = (float*)d_out;

    gnn_fused<<<GRID, BLOCK, 0, stream>>>(x, mp_w, mp_b, attn_w,
                                          ln_g, ln_b, cls_w, cls_b, out);
}

// Round 6
// 34.565 us; speedup vs baseline: 1.1752x; 1.1752x over previous
//
#include <hip/hip_runtime.h>
#include <math.h>
#include <stdint.h>

namespace {

constexpr int kB = 16384;
constexpr int kN = 12;
constexpr int kD = 64;
constexpr int kL = 2;
constexpr int kH = kN * kD;          // 768
constexpr float kEps = 1e-5f;

constexpr int WAVES_PER_BLOCK = 4;
constexpr int BLOCK = 64 * WAVES_PER_BLOCK;        // 256
constexpr int GRID  = kB / (4 * WAVES_PER_BLOCK);  // 1024 -> 4 graphs/wave

typedef _Float16 half2v __attribute__((ext_vector_type(2)));

__device__ __forceinline__ uint32_t pack_f16(float a, float b) {
    auto p = __builtin_amdgcn_cvt_pkrtz(a, b);
    return __builtin_bit_cast(uint32_t, p);
}
__device__ __forceinline__ float fdot2(uint32_t a, uint32_t b, float c) {
    return __builtin_amdgcn_fdot2(__builtin_bit_cast(half2v, a),
                                  __builtin_bit_cast(half2v, b), c, false);
}

// x += row_ror:N of x (within the 16-lane DPP row).
template<int N>
__device__ __forceinline__ float dpp_ror_add(float x) {
    int r = __builtin_amdgcn_update_dpp(0, __builtin_bit_cast(int, x),
                                        0x120 + N, 0xF, 0xF, true);
    return x + __builtin_bit_cast(float, r);
}
// Sum over the 16-lane row; every lane ends with the total. DPP-only (no LDS).
__device__ __forceinline__ float rowSum16(float x) {
    x = dpp_ror_add<8>(x);
    x = dpp_ror_add<4>(x);
    x = dpp_ror_add<2>(x);
    x = dpp_ror_add<1>(x);
    return x;
}

// tanh-form GELU (max err vs exact ~1.5e-3, overflow-graceful).
__device__ __forceinline__ float fast_gelu(float x) {
    const float x2 = x * x;
    const float y  = x * fmaf(x2, 0.0356774081f, 0.7978845608f);
    const float e  = __expf(2.0f * y);
    const float r  = __builtin_amdgcn_rcpf(e + 1.0f);
    const float t  = fmaf(-2.0f, r, 1.0f);      // tanh(y)
    const float hx = 0.5f * x;
    return fmaf(hx, t, hx);
}

__global__ __launch_bounds__(BLOCK, 4)
void gnn_fused(const float* __restrict__ x,
               const float* __restrict__ mp_w,
               const float* __restrict__ mp_b,
               const float* __restrict__ attn_w,
               const float* __restrict__ ln_g,
               const float* __restrict__ ln_b,
               const float* __restrict__ cls_w,
               const float* __restrict__ cls_b,
               float* __restrict__ out)
{
    // WIu entry (l,d4,e) at index ((l*16+d4)*64 + (e ^ ((d4&15)<<2))) * 2:
    // uint2 = { h2(W[4d4+0][e], W[4d4+1][e]), h2(W[4d4+2][e], W[4d4+3][e]) }
    // with W[d][e] = mp_w[l][e][d].  XOR swizzle spreads the staging writes
    // across banks; reads XOR with a d4-constant -> still contiguous in e.
    __shared__ __align__(16) uint32_t WIu[kL * 16 * kD * 2];   // 16 KB
    __shared__ __align__(16) float w2s[kL][kD];
    __shared__ __align__(16) float mpb[kL][kD];
    __shared__ __align__(16) float lng[kL][kD];
    __shared__ __align__(16) float lnb[kL][kD];
    __shared__ __align__(16) uint32_t qpu[WAVES_PER_BLOCK][4][2 * 16 + 4];

    const int tid  = threadIdx.x;
    const int lane = tid & 63;
    const int wid  = tid >> 6;
    const int grp  = lane >> 4;        // graph slot in wave (0..3) = DPP row
    const int sub  = lane & 15;        // lane in graph; owns feats 4sub..4sub+3
    const int b    = (blockIdx.x * WAVES_PER_BLOCK + wid) * 4 + grp;

    // ---- issue x loads early (overlap with LDS staging) ----
    float4 h4[kN];
    const float* xb = x + b * kH + 4 * sub;
#pragma unroll
    for (int n = 0; n < kN; ++n)
        h4[n] = *(const float4*)(xb + n * kD);

    // ---- stage W (f16-packed, swizzled) + params ----
    for (int i = tid; i < kL * kD * 16; i += BLOCK) {
        const int d4 = i & 15;
        const int e  = (i >> 4) & 63;
        const int l  = i >> 10;
        const float4 w = *(const float4*)&mp_w[(l * kD + e) * kD + 4 * d4]; // coalesced
        uint2 pk;
        pk.x = pack_f16(w.x, w.y);
        pk.y = pack_f16(w.z, w.w);
        const int eidx = e ^ ((d4 & 15) << 2);
        *(uint2*)&WIu[((l * 16 + d4) * kD + eidx) * 2] = pk;
    }
    for (int i = tid; i < kL * kD; i += BLOCK) {
        const int l = i >> 6, d = i & 63;
        w2s[l][d] = attn_w[l * (2 * kD) + kD + d];  // w2 half; w1 + attn_b cancel in softmax
        mpb[l][d] = mp_b[i];
        lng[l][d] = ln_g[i];
        lnb[l][d] = ln_b[i];
    }
    __syncthreads();

#pragma unroll
    for (int l = 0; l < kL; ++l) {
        const float4 w2v = *(const float4*)&w2s[l][4 * sub];

        // ---- ej -> exp -> sum & q, fused. |ej| <~ 1 (w2 scale 0.02): no max sub.
        float sum = 0.f;
        float4 q = make_float4(0.f, 0.f, 0.f, 0.f);
#pragma unroll
        for (int n = 0; n < kN; ++n) {
            float v = h4[n].x * w2v.x;
            v = fmaf(h4[n].y, w2v.y, v);
            v = fmaf(h4[n].z, w2v.z, v);
            v = fmaf(h4[n].w, w2v.w, v);
            v = rowSum16(v);                 // ej[n], uniform in group
            const float sn = __expf(v);
            sum += sn;
            q.x = fmaf(sn, h4[n].x, q.x);
            q.y = fmaf(sn, h4[n].y, q.y);
            q.z = fmaf(sn, h4[n].z, q.z);
            q.w = fmaf(sn, h4[n].w, q.w);
        }
        const float inv = __builtin_amdgcn_rcpf(sum);

        // publish q (f16 pairs); entry j of the row = feats {2j, 2j+1}
        uint2 qp;
        qp.x = pack_f16(q.x, q.y);
        qp.y = pack_f16(q.z, q.w);
        *(uint2*)&qpu[wid][grp][2 * sub] = qp;
        __builtin_amdgcn_wave_barrier();

        // ---- agg[e] = inv * sum_d q[d] W[d][e] + mp_b[e]; lane owns e=4sub..+3
        float c0 = 0.f, c1 = 0.f, c2 = 0.f, c3 = 0.f;
        const uint32_t* qrow = &qpu[wid][grp][0];
        const int ex = 4 * sub;
#pragma unroll
        for (int d8 = 0; d8 < 8; ++d8) {
            const uint4 qv = *(const uint4*)&qrow[4 * d8];   // q for d4=2d8, 2d8+1
            {
                const int d4 = 2 * d8;
                const uint32_t* wb =
                    &WIu[((l * 16 + d4) * kD + (ex ^ ((d4 & 15) << 2))) * 2];
                const uint4 r0 = *(const uint4*)&wb[0];   // e = ex, ex+1
                const uint4 r1 = *(const uint4*)&wb[4];   // e = ex+2, ex+3
                c0 = fdot2(qv.x, r0.x, c0); c0 = fdot2(qv.y, r0.y, c0);
                c1 = fdot2(qv.x, r0.z, c1); c1 = fdot2(qv.y, r0.w, c1);
                c2 = fdot2(qv.x, r1.x, c2); c2 = fdot2(qv.y, r1.y, c2);
                c3 = fdot2(qv.x, r1.z, c3); c3 = fdot2(qv.y, r1.w, c3);
            }
            {
                const int d4 = 2 * d8 + 1;
                const uint32_t* wb =
                    &WIu[((l * 16 + d4) * kD + (ex ^ ((d4 & 15) << 2))) * 2];
                const uint4 r0 = *(const uint4*)&wb[0];
                const uint4 r1 = *(const uint4*)&wb[4];
                c0 = fdot2(qv.z, r0.x, c0); c0 = fdot2(qv.w, r0.y, c0);
                c1 = fdot2(qv.z, r0.z, c1); c1 = fdot2(qv.w, r0.w, c1);
                c2 = fdot2(qv.z, r1.x, c2); c2 = fdot2(qv.w, r1.y, c2);
                c3 = fdot2(qv.z, r1.z, c3); c3 = fdot2(qv.w, r1.w, c3);
            }
        }
        const float4 mb4 = *(const float4*)&mpb[l][4 * sub];
        const float4 cc = make_float4(fmaf(c0, inv, mb4.x), fmaf(c1, inv, mb4.y),
                                      fmaf(c2, inv, mb4.z), fmaf(c3, inv, mb4.w));

        // ---- residual + GELU + LayerNorm ----
        const float4 g4 = *(const float4*)&lng[l][4 * sub];
        const float4 b4 = *(const float4*)&lnb[l][4 * sub];
#pragma unroll
        for (int n = 0; n < kN; ++n) {
            const float ge0 = fast_gelu(h4[n].x + cc.x);
            const float ge1 = fast_gelu(h4[n].y + cc.y);
            const float ge2 = fast_gelu(h4[n].z + cc.z);
            const float ge3 = fast_gelu(h4[n].w + cc.w);
            float s1 = (ge0 + ge1) + (ge2 + ge3);
            float s2 = ge0 * ge0;
            s2 = fmaf(ge1, ge1, s2);
            s2 = fmaf(ge2, ge2, s2);
            s2 = fmaf(ge3, ge3, s2);
            s1 = rowSum16(s1);
            s2 = rowSum16(s2);
            const float mu  = s1 * (1.f / 64.f);
            const float var = fmaf(s2, 1.f / 64.f, -mu * mu);
            const float rs  = __builtin_amdgcn_rsqf(var + kEps);
            h4[n].x = fmaf(ge0 - mu, rs * g4.x, b4.x);
            h4[n].y = fmaf(ge1 - mu, rs * g4.y, b4.y);
            h4[n].z = fmaf(ge2 - mu, rs * g4.z, b4.z);
            h4[n].w = fmaf(ge3 - mu, rs * g4.w, b4.w);
        }
    }

    // ---- classifier: out[b][c] = <h, cls_w[c]> + cls_b[c] ----
    float p[4] = {0.f, 0.f, 0.f, 0.f};
#pragma unroll
    for (int n = 0; n < kN; ++n) {
        const int base = n * kD + 4 * sub;
#pragma unroll
        for (int c = 0; c < 4; ++c) {
            const float4 cw = *(const float4*)(cls_w + c * kH + base);
            p[c] = fmaf(h4[n].x, cw.x, p[c]);
            p[c] = fmaf(h4[n].y, cw.y, p[c]);
            p[c] = fmaf(h4[n].z, cw.z, p[c]);
            p[c] = fmaf(h4[n].w, cw.w, p[c]);
        }
    }
#pragma unroll
    for (int c = 0; c < 4; ++c) p[c] = rowSum16(p[c]);

    if (sub == 0) {
        const float4 cb = *(const float4*)cls_b;
        *(float4*)&out[b * 4] = make_float4(p[0] + cb.x, p[1] + cb.y,
                                            p[2] + cb.z, p[3] + cb.w);
    }
}

} // namespace

extern "C" void kernel_launch(void* const* d_in, const int* in_sizes, int n_in,
                              void* d_out, int out_size, void* d_ws, size_t ws_size,
                              hipStream_t stream)
{
    const float* x      = (const float*)d_in[0];
    const float* mp_w   = (const float*)d_in[1];
    const float* mp_b   = (const float*)d_in[2];
    const float* attn_w = (const float*)d_in[3];
    // d_in[4] = attn_b : cancels in softmax, unused
    const float* ln_g   = (const float*)d_in[5];
    const float* ln_b   = (const float*)d_in[6];
    const float* cls_w  = (const float*)d_in[7];
    const float* cls_b  = (const float*)d_in[8];
    float* out = (float*)d_out;

    gnn_fused<<<GRID, BLOCK, 0, stream>>>(x, mp_w, mp_b, attn_w,
                                          ln_g, ln_b, cls_w, cls_b, out);
}